// Round 1
// baseline (113.948 us; speedup 1.0000x reference)
//
#include <hip/hip_runtime.h>
#include <hip/hip_bf16.h>
#include <stdint.h>

#define BATCH 32
#define CIN   256
#define COUT  256
#define HDIM  56
#define HW    3136   // 56*56
#define NPAD  3200   // pad HW to multiple of 128

typedef short bf16x8 __attribute__((ext_vector_type(8)));
typedef float f32x4  __attribute__((ext_vector_type(4)));

__device__ __forceinline__ unsigned short f2bf(float f) {
    unsigned u = __float_as_uint(f);
    u += 0x7fffu + ((u >> 16) & 1u);   // round-to-nearest-even
    return (unsigned short)(u >> 16);
}

// ---------------- K0: fold BN2 into pointwise weights, zero pwmax ----------
__global__ __launch_bounds__(256) void prep_kernel(
        const float* __restrict__ pw_w, const float* __restrict__ pw_b,
        const float* __restrict__ g2, const float* __restrict__ be2,
        const float* __restrict__ mu2, const float* __restrict__ va2,
        unsigned short* __restrict__ Wp, float* __restrict__ b2,
        unsigned* __restrict__ pwmax) {
    int o = blockIdx.x;
    int t = threadIdx.x;
    float inv2 = g2[o] * rsqrtf(va2[o] + 1e-5f);
    Wp[o * CIN + t] = f2bf(pw_w[o * CIN + t] * inv2);
    if (t == 0) b2[o] = pw_b[o] * inv2 + be2[o] - mu2[o] * inv2;
    int idx = blockIdx.x * 256 + t;
    if (idx < BATCH * COUT) pwmax[idx] = 0u;
}

// ---------------- K1: depthwise 3x3 + BN1 + ReLU + plane cut -> y bf16 -----
__global__ __launch_bounds__(256) void dw_kernel(
        const float* __restrict__ x, const float* __restrict__ dww,
        const float* __restrict__ dwb,
        const float* __restrict__ g1, const float* __restrict__ be1,
        const float* __restrict__ mu1, const float* __restrict__ va1,
        unsigned short* __restrict__ y) {
    int blk = blockIdx.x;
    int c = blk & 255;
    int b = blk >> 8;
    int tid = threadIdx.x;

    __shared__ float xs[58 * 58];
    __shared__ float red[4];
    __shared__ float bmax_sh;

    const float* xp = x + (size_t)(b * CIN + c) * HW;
    for (int idx = tid; idx < 58 * 58; idx += 256) {
        int r = idx / 58;
        int q = idx - r * 58;
        int gr = r - 1, gc = q - 1;
        float v = 0.f;
        if ((unsigned)gr < 56u && (unsigned)gc < 56u) v = xp[gr * 56 + gc];
        xs[idx] = v;
    }

    float w0 = dww[c * 9 + 0], w1 = dww[c * 9 + 1], w2 = dww[c * 9 + 2];
    float w3 = dww[c * 9 + 3], w4 = dww[c * 9 + 4], w5 = dww[c * 9 + 5];
    float w6 = dww[c * 9 + 6], w7 = dww[c * 9 + 7], w8 = dww[c * 9 + 8];
    float bias = dwb[c];
    float inv = g1[c] * rsqrtf(va1[c] + 1e-5f);
    float sh  = be1[c] - mu1[c] * inv;
    __syncthreads();

    float vals[13];
    float lmax = 0.f;
#pragma unroll
    for (int i = 0; i < 13; ++i) {
        int p = tid + i * 256;
        float v = 0.f;
        if (p < HW) {
            int h = p / 56;
            int w = p - h * 56;
            const float* bp = &xs[h * 58 + w];
            float a = bp[0] * w0 + bp[1] * w1 + bp[2] * w2
                    + bp[58] * w3 + bp[59] * w4 + bp[60] * w5
                    + bp[116] * w6 + bp[117] * w7 + bp[118] * w8;
            v = (a + bias) * inv + sh;
            v = fmaxf(v, 0.f);
            lmax = fmaxf(lmax, v);
        }
        vals[i] = v;
    }
    // block-wide max reduce
    for (int off = 32; off >= 1; off >>= 1)
        lmax = fmaxf(lmax, __shfl_xor(lmax, off, 64));
    if ((tid & 63) == 0) red[tid >> 6] = lmax;
    __syncthreads();
    if (tid == 0) bmax_sh = fmaxf(fmaxf(red[0], red[1]), fmaxf(red[2], red[3]));
    __syncthreads();
    bool cut = (bmax_sh < 4.0f);

    unsigned short* yp = y + (size_t)(b * CIN + c) * NPAD;
#pragma unroll
    for (int i = 0; i < 13; ++i) {
        int p = tid + i * 256;
        if (p < HW) yp[p] = cut ? (unsigned short)0 : f2bf(vals[i]);
    }
    if (tid < NPAD - HW) yp[HW + tid] = 0;  // zero padding columns
}

// ---------------- K2: pointwise GEMM (bf16 MFMA) + BN2 + ReLU + row max ----
// Z_b (O x HW) = W' (O x C) * Y_b (C x HW)
#define MT 128
#define NT 128
#define KS 64

__global__ __launch_bounds__(256) void pw_kernel(
        const unsigned short* __restrict__ y, const unsigned short* __restrict__ Wp,
        const float* __restrict__ b2, float* __restrict__ z,
        unsigned* __restrict__ pwmax) {
    __shared__ __align__(16) unsigned short Al[MT * KS];  // [m][k], chunk-swizzled by (m&7)
    __shared__ __align__(16) unsigned short Bl[NT * KS];  // [n][k], chunk-swizzled by ((n>>2)&7)

    int bid = blockIdx.x;
    int mt = bid & 1;
    int rest = bid >> 1;
    int nt = rest % 25;
    int b = rest / 25;
    int m0 = mt * 128, n0 = nt * 128;

    int tid = threadIdx.x;
    int lane = tid & 63, wid = tid >> 6;
    int wm = (wid & 1) * 64, wn = (wid >> 1) * 64;
    int l15 = lane & 15, l4 = lane >> 4;

    f32x4 acc[4][4];
#pragma unroll
    for (int mf = 0; mf < 4; ++mf)
#pragma unroll
        for (int nf = 0; nf < 4; ++nf) acc[mf][nf] = {0.f, 0.f, 0.f, 0.f};

    const unsigned short* yb = y + (size_t)b * CIN * NPAD;

    for (int kk = 0; kk < 4; ++kk) {
        int k0 = kk * 64;
        __syncthreads();  // previous compute done before overwriting LDS
        // stage A: 1024 16B-slots, 4 per thread. storage chunk c holds data chunk c^(m&7)
#pragma unroll
        for (int i = 0; i < 4; ++i) {
            int s = tid + i * 256;
            int m = s >> 3, cch = s & 7;
            int dch = cch ^ (m & 7);
            uint4 v = *(const uint4*)(Wp + (size_t)(m0 + m) * CIN + k0 + dch * 8);
            *(uint4*)((char*)Al + m * 128 + cch * 16) = v;
        }
        // stage B with transpose: unit = 4 k-rows x 4 n-cols
#pragma unroll
        for (int i = 0; i < 2; ++i) {
            int u = tid + i * 256;
            int q = u >> 5, nq = u & 31;  // q: k-quad 0..15, nq: n-quad 0..31
            const unsigned short* src = yb + (size_t)(k0 + q * 4) * NPAD + n0 + nq * 4;
            uint2 r0 = *(const uint2*)(src);
            uint2 r1 = *(const uint2*)(src + NPAD);
            uint2 r2 = *(const uint2*)(src + 2 * NPAD);
            uint2 r3 = *(const uint2*)(src + 3 * NPAD);
#pragma unroll
            for (int i2 = 0; i2 < 4; ++i2) {
                unsigned x0 = (i2 & 2) ? r0.y : r0.x;
                unsigned x1 = (i2 & 2) ? r1.y : r1.x;
                unsigned x2 = (i2 & 2) ? r2.y : r2.x;
                unsigned x3 = (i2 & 2) ? r3.y : r3.x;
                if (i2 & 1) { x0 >>= 16; x2 >>= 16; }
                else        { x0 &= 0xffffu; x2 &= 0xffffu; }
                unsigned px = (i2 & 1) ? (x0 | (x1 & 0xffff0000u))
                                       : (x0 | (x1 << 16));
                unsigned py = (i2 & 1) ? (x2 | (x3 & 0xffff0000u))
                                       : (x2 | (x3 << 16));
                int nloc = nq * 4 + i2;
                int sb = nloc * 128 + (((q >> 1) ^ ((nloc >> 2) & 7)) << 4) + ((q & 1) << 3);
                *(uint2*)((char*)Bl + sb) = make_uint2(px, py);
            }
        }
        __syncthreads();
        // compute: 2 mfma-K halves of 32
#pragma unroll
        for (int h = 0; h < 2; ++h) {
            bf16x8 af[4], bfr[4];
            int cc = h * 4 + l4;
#pragma unroll
            for (int mf = 0; mf < 4; ++mf) {
                int m = wm + mf * 16 + l15;
                af[mf] = *(const bf16x8*)((const char*)Al + m * 128 + ((cc ^ (m & 7)) << 4));
            }
#pragma unroll
            for (int nf = 0; nf < 4; ++nf) {
                int n = wn + nf * 16 + l15;
                bfr[nf] = *(const bf16x8*)((const char*)Bl + n * 128 + ((cc ^ ((n >> 2) & 7)) << 4));
            }
#pragma unroll
            for (int mf = 0; mf < 4; ++mf)
#pragma unroll
                for (int nf = 0; nf < 4; ++nf)
                    acc[mf][nf] = __builtin_amdgcn_mfma_f32_16x16x32_bf16(
                        af[mf], bfr[nf], acc[mf][nf], 0, 0, 0);
        }
    }

    // epilogue: bias + relu + store + per-o-row plane max (atomic)
    float* zb = z + (size_t)b * COUT * HW;
#pragma unroll
    for (int mf = 0; mf < 4; ++mf) {
        int obase = m0 + wm + mf * 16 + l4 * 4;
        float bb0 = b2[obase + 0], bb1 = b2[obase + 1];
        float bb2v = b2[obase + 2], bb3 = b2[obase + 3];
        float rmax[4] = {0.f, 0.f, 0.f, 0.f};
#pragma unroll
        for (int nf = 0; nf < 4; ++nf) {
            int n = n0 + wn + nf * 16 + l15;
            bool valid = (n < HW);
            float v0 = fmaxf(acc[mf][nf][0] + bb0, 0.f);
            float v1 = fmaxf(acc[mf][nf][1] + bb1, 0.f);
            float v2 = fmaxf(acc[mf][nf][2] + bb2v, 0.f);
            float v3 = fmaxf(acc[mf][nf][3] + bb3, 0.f);
            if (valid) {
                zb[(size_t)(obase + 0) * HW + n] = v0;
                zb[(size_t)(obase + 1) * HW + n] = v1;
                zb[(size_t)(obase + 2) * HW + n] = v2;
                zb[(size_t)(obase + 3) * HW + n] = v3;
                rmax[0] = fmaxf(rmax[0], v0);
                rmax[1] = fmaxf(rmax[1], v1);
                rmax[2] = fmaxf(rmax[2], v2);
                rmax[3] = fmaxf(rmax[3], v3);
            }
        }
#pragma unroll
        for (int r = 0; r < 4; ++r) {
            float v = rmax[r];
            v = fmaxf(v, __shfl_xor(v, 1, 64));
            v = fmaxf(v, __shfl_xor(v, 2, 64));
            v = fmaxf(v, __shfl_xor(v, 4, 64));
            v = fmaxf(v, __shfl_xor(v, 8, 64));
            if (l15 == 0)
                atomicMax(&pwmax[b * COUT + obase + r], __float_as_uint(v));
        }
    }
}

// ---------------- K3: apply pointwise cut ---------------------------------
__global__ __launch_bounds__(256) void cut_kernel(const unsigned* __restrict__ pwmax,
                                                  float* __restrict__ z) {
    int bo = blockIdx.x;
    if (__uint_as_float(pwmax[bo]) >= 1e-3f) return;
    float4* zp = (float4*)(z + (size_t)bo * HW);
    for (int i = threadIdx.x; i < HW / 4; i += 256)
        zp[i] = make_float4(0.f, 0.f, 0.f, 0.f);
}

extern "C" void kernel_launch(void* const* d_in, const int* in_sizes, int n_in,
                              void* d_out, int out_size, void* d_ws, size_t ws_size,
                              hipStream_t stream) {
    const float* x   = (const float*)d_in[0];
    const float* dww = (const float*)d_in[1];
    const float* dwb = (const float*)d_in[2];
    const float* g1  = (const float*)d_in[3];
    const float* be1 = (const float*)d_in[4];
    const float* mu1 = (const float*)d_in[5];
    const float* va1 = (const float*)d_in[6];
    const float* pww = (const float*)d_in[7];
    const float* pwb = (const float*)d_in[8];
    const float* g2  = (const float*)d_in[9];
    const float* be2 = (const float*)d_in[10];
    const float* mu2 = (const float*)d_in[11];
    const float* va2 = (const float*)d_in[12];
    float* z = (float*)d_out;

    char* ws = (char*)d_ws;
    const size_t Y_BYTES = (size_t)BATCH * CIN * NPAD * 2;  // 52,428,800
    unsigned short* y  = (unsigned short*)ws;
    unsigned short* Wp = (unsigned short*)(ws + Y_BYTES);
    float* b2          = (float*)(ws + Y_BYTES + 131072);
    unsigned* pwmax    = (unsigned*)(ws + Y_BYTES + 131072 + 1024);

    prep_kernel<<<256, 256, 0, stream>>>(pww, pwb, g2, be2, mu2, va2, Wp, b2, pwmax);
    dw_kernel<<<BATCH * CIN, 256, 0, stream>>>(x, dww, dwb, g1, be1, mu1, va1, y);
    pw_kernel<<<2 * 25 * BATCH, 256, 0, stream>>>(y, Wp, b2, z, pwmax);
    cut_kernel<<<BATCH * COUT, 256, 0, stream>>>(pwmax, z);
}